// Round 8
// baseline (346.320 us; speedup 1.0000x reference)
//
#include <hip/hip_runtime.h>
#include <hip/hip_bf16.h>
#include <cstdint>
#include <cstddef>

typedef __attribute__((ext_vector_type(4))) float f32x4;
typedef __attribute__((ext_vector_type(8))) short short8;
typedef __attribute__((ext_vector_type(4))) unsigned short u16x4;

static constexpr int NEDGE = 1600000;
static constexpr int NNODE = 50000;
static constexpr float AVG_LOG_F = 3.4295121912749508f;

// GEMM tile: 48 rows -> 50 KB LDS -> 3 blocks/CU (was 64 rows / 66.5 KB / 2)
static constexpr int TM = 48;
static constexpr int NBLK = (NNODE + TM - 1) / TM;   // 1042 (covers 50016)

// ---- workspace layout (bytes) ----
static constexpr size_t CNT_OFF  = 0;          // 50000 i32
static constexpr size_t RS_OFF   = 200000;     // 50001 i32
static constexpr size_t BS_OFF   = 400064;     // 32 i32
static constexpr size_t RANK_OFF = 400192;     // 1600000 i32
static constexpr size_t CSR_OFF  = 6800192;    // 1600000 i32
static constexpr size_t LDF_OFF  = 13200192;   // 50000 f32
static constexpr size_t AF_OFF   = 13400192;   // 50000 f32
static constexpr size_t BT_OFF   = 13600192;   // 384*512 bf16
static constexpr size_t A_OFF    = 13993408;   // 50048*512 bf16

__device__ __forceinline__ unsigned short f2bf(float f){
  union { __hip_bfloat16 h; unsigned short u; } cv;
  cv.h = __float2bfloat16(f);
  return cv.u;
}

// buildB + zero(cnt) + zero(A pad rows) in one launch (all independent preludes)
// Bt[ncol][k]: ncol = s*128 + b*32 + l ; k = t*128 + p*32 + f
// Bt = sum_i rule[i,p,b] * W[i, s*128+t*32+f, l]
__global__ void k_buildB_zero(const float* __restrict__ rule, const float* __restrict__ W,
                              unsigned short* __restrict__ Bt,
                              int* __restrict__ cnt, int* __restrict__ apad){
  int id = blockIdx.x * 256 + threadIdx.x;
  if (id < NNODE) cnt[id] = 0;
  if (id < 48 * 256) apad[id] = 0;
  if (id >= 384 * 512) return;
  int k    = id & 511;
  int ncol = id >> 9;
  int t  = k >> 7;      int xf = k & 127;
  int p  = xf >> 5;     int f  = xf & 31;
  int s  = ncol >> 7;   int j  = ncol & 127;
  int bb = j >> 5;      int l  = j & 31;
  int kw = s * 128 + t * 32 + f;
  float acc = 0.f;
  #pragma unroll
  for (int i = 0; i < 4; ++i)
    acc += rule[i * 16 + p * 4 + bb] * W[(i * 384 + kw) * 32 + l];
  Bt[(size_t)ncol * 512 + k] = f2bf(acc);
}

// histogram + per-edge rank, 4 edges/thread
__global__ void k_hist(const int4* __restrict__ idx4, int* __restrict__ cnt,
                       int4* __restrict__ rank4){
  int e4 = blockIdx.x * 256 + threadIdx.x;
  if (e4 < NEDGE / 4){
    int4 n = idx4[e4];
    int4 r;
    r.x = atomicAdd(&cnt[n.x], 1);
    r.y = atomicAdd(&cnt[n.y], 1);
    r.z = atomicAdd(&cnt[n.z], 1);
    r.w = atomicAdd(&cnt[n.w], 1);
    rank4[e4] = r;
  }
}

__global__ void k_scan1(const int* __restrict__ cnt, int* __restrict__ rs, int* __restrict__ bs){
  __shared__ int lds[256];
  int t = threadIdx.x;
  int base = blockIdx.x * 2048 + t * 8;
  int v[8]; int s = 0;
  #pragma unroll
  for (int j = 0; j < 8; ++j){
    int i = base + j;
    int val = (i < NNODE) ? cnt[i] : 0;
    v[j] = val; s += val;
  }
  lds[t] = s;
  __syncthreads();
  for (int off = 1; off < 256; off <<= 1){
    int add = (t >= off) ? lds[t - off] : 0;
    __syncthreads();
    lds[t] += add;
    __syncthreads();
  }
  int run = lds[t] - s;   // exclusive prefix for this thread
  #pragma unroll
  for (int j = 0; j < 8; ++j){
    int i = base + j;
    if (i < NNODE) rs[i] = run;
    run += v[j];
  }
  if (t == 255) bs[blockIdx.x] = lds[255];
}

// adds block offsets; each block locally scans the 25 block-sums
__global__ void k_scan3(int* __restrict__ rs, const int* __restrict__ bs){
  __shared__ int pref[32];
  int t = threadIdx.x;
  if (t < 32){
    int v = (t < 25) ? bs[t] : 0;
    #pragma unroll
    for (int off = 1; off < 32; off <<= 1){
      int u = __shfl_up(v, off);
      if (t >= off) v += u;
    }
    pref[t] = v;  // inclusive scan
  }
  __syncthreads();
  int i = blockIdx.x * 256 + t;
  if (i < NNODE){
    int b = i >> 11;
    int add = (b == 0) ? 0 : pref[b - 1];
    rs[i] += add;
  }
  if (i == 0) rs[NNODE] = NEDGE;
}

// atomic-free scatter, 4 edges/thread
__global__ void k_scatter(const int4* __restrict__ idx4, const int4* __restrict__ rank4,
                          const int* __restrict__ rs, int* __restrict__ csr){
  int e4 = blockIdx.x * 256 + threadIdx.x;
  if (e4 < NEDGE / 4){
    int4 n = idx4[e4];
    int4 r = rank4[e4];
    int e = e4 * 4;
    csr[rs[n.x] + r.x] = e + 0;
    csr[rs[n.y] + r.y] = e + 1;
    csr[rs[n.z] + r.z] = e + 2;
    csr[rs[n.w] + r.w] = e + 3;
  }
}

// one wave per node: gather edges via CSR, compute mean/min/max/std per feature
__global__ __launch_bounds__(256) void k_stats(const float* __restrict__ x,
                const int* __restrict__ csr, const int* __restrict__ rs,
                unsigned short* __restrict__ A, float* __restrict__ ldf, float* __restrict__ af){
  int wid  = blockIdx.x * 4 + (threadIdx.x >> 6);
  int lane = threadIdx.x & 63;
  if (wid >= NNODE) return;
  int s0 = rs[wid], s1 = rs[wid + 1];
  int deg = s1 - s0;
  int sub = lane >> 5;          // which edge of the pair
  int fl  = (lane & 31) * 4;    // feature offset (4 floats)
  f32x4 sum = {0.f,0.f,0.f,0.f}, ssq = {0.f,0.f,0.f,0.f};
  float inf = __builtin_inff();
  f32x4 mn = {inf,inf,inf,inf}, mx = {-inf,-inf,-inf,-inf};
  for (int base = s0; base < s1; base += 64){
    int m = min(64, s1 - base);
    int myE = (lane < m) ? csr[base + lane] : 0;
    int pairs = (m + 1) >> 1;
    #pragma unroll 16
    for (int j = 0; j < pairs; ++j){
      int sl = j * 2 + sub;
      int ed = __shfl(myE, sl);
      // x rows are read exactly once -> keep them out of L2 (non-temporal)
      f32x4 v = __builtin_nontemporal_load((const f32x4*)(x + (size_t)ed * 128 + fl));
      if (sl < m){
        sum += v;
        ssq += v * v;
        #pragma unroll
        for (int c = 0; c < 4; ++c){ mn[c] = fminf(mn[c], v[c]); mx[c] = fmaxf(mx[c], v[c]); }
      }
    }
  }
  // merge the two half-wave partials (lane i <-> i^32 hold same features)
  #pragma unroll
  for (int c = 0; c < 4; ++c){
    sum[c] += __shfl_xor(sum[c], 32);
    ssq[c] += __shfl_xor(ssq[c], 32);
    mn[c]  = fminf(mn[c], __shfl_xor(mn[c], 32));
    mx[c]  = fmaxf(mx[c], __shfl_xor(mx[c], 32));
  }
  if (lane < 32){
    float invd = (deg > 0) ? (1.0f / (float)deg) : 1.0f;
    unsigned short* Arow = A + (size_t)wid * 512;
    u16x4 stv[4];
    #pragma unroll
    for (int c = 0; c < 4; ++c){
      float mean = sum[c] * invd;
      float var  = ssq[c] * invd - mean * mean;
      float sd   = sqrtf(fmaxf(var, 0.f) + 1e-5f);
      float lo   = (deg > 0) ? mn[c] : 0.f;
      float hi   = (deg > 0) ? mx[c] : 0.f;
      stv[0][c] = f2bf(mean);
      stv[1][c] = f2bf(lo);
      stv[2][c] = f2bf(hi);
      stv[3][c] = f2bf(sd);
    }
    #pragma unroll
    for (int t = 0; t < 4; ++t)
      *(u16x4*)(Arow + t * 128 + fl) = stv[t];
  }
  if (lane == 0){
    float ld = logf((float)deg + 1.0f);
    ldf[wid] = ld / AVG_LOG_F;
    af[wid]  = (deg == 0) ? 1.0f : (AVG_LOG_F / ld);
  }
}

// Fused GEMM + degree-scaler combine. 48-row tile (50 KB LDS -> 3 blocks/CU).
// A-tile staged once per block in LDS, stride 520 halves (conflict-free-ish).
__global__ __launch_bounds__(256) void k_gemm_fused(const unsigned short* __restrict__ A,
                                                    const unsigned short* __restrict__ Bt,
                                                    const float* __restrict__ ldf,
                                                    const float* __restrict__ af,
                                                    const float* __restrict__ bias,
                                                    float* __restrict__ out){
  __shared__ unsigned short Alds[TM * 520];   // 49920 B
  int w = threadIdx.x >> 6, lane = threadIdx.x & 63;
  int m0 = blockIdx.x * TM;
  int j0 = w * 32;
  int r16 = lane & 15, kq = lane >> 4;
  // stage A: 48 rows x 512 k = 48 KB; 256 threads x 16B x 12 iters, coalesced
  {
    const unsigned short* src = A + (size_t)m0 * 512;
    int t = threadIdx.x;
    #pragma unroll
    for (int i = 0; i < 12; ++i){
      int off8 = (i * 256 + t) * 8;          // element offset, linear in source
      int r = off8 >> 9, c = off8 & 511;
      short8 v = *(const short8*)(src + off8);
      *(short8*)(&Alds[r * 520 + c]) = v;
    }
  }
  __syncthreads();
  f32x4 acc[3][2][3];   // [m-frag][col-frag][segment]
  #pragma unroll
  for (int m = 0; m < 3; ++m)
    #pragma unroll
    for (int nj = 0; nj < 2; ++nj)
      #pragma unroll
      for (int s = 0; s < 3; ++s) acc[m][nj][s] = (f32x4){0.f,0.f,0.f,0.f};
  const unsigned short* Bb = Bt + (size_t)(j0 + r16) * 512 + kq * 8;
  const unsigned short* Al = Alds + (size_t)r16 * 520 + kq * 8;
  for (int kk = 0; kk < 512; kk += 32){
    short8 a[3];
    #pragma unroll
    for (int m = 0; m < 3; ++m) a[m] = *(const short8*)(Al + m * 16 * 520 + kk);
    short8 b[3][2];
    #pragma unroll
    for (int s = 0; s < 3; ++s)
      #pragma unroll
      for (int nj = 0; nj < 2; ++nj)
        b[s][nj] = *(const short8*)(Bb + (size_t)(s * 128 + nj * 16) * 512 + kk);
    #pragma unroll
    for (int m = 0; m < 3; ++m)
      #pragma unroll
      for (int nj = 0; nj < 2; ++nj)
        #pragma unroll
        for (int s = 0; s < 3; ++s)
          acc[m][nj][s] = __builtin_amdgcn_mfma_f32_16x16x32_bf16(a[m], b[s][nj], acc[m][nj][s], 0, 0, 0);
  }
  int rq = kq;
  #pragma unroll
  for (int m = 0; m < 3; ++m){
    int row0 = m0 + m * 16 + rq * 4;
    float lv[4], av[4];
    #pragma unroll
    for (int r = 0; r < 4; ++r){
      int rr = min(row0 + r, NNODE - 1);
      lv[r] = ldf[rr];
      av[r] = af[rr];
    }
    #pragma unroll
    for (int nj = 0; nj < 2; ++nj){
      int col = j0 + nj * 16 + r16;
      float bb = bias[col];
      #pragma unroll
      for (int r = 0; r < 4; ++r){
        int row = row0 + r;
        if (row < NNODE)
          out[(size_t)row * 128 + col] =
            acc[m][nj][0][r] + lv[r] * acc[m][nj][1][r] + av[r] * acc[m][nj][2][r] + bb;
      }
    }
  }
}

extern "C" void kernel_launch(void* const* d_in, const int* in_sizes, int n_in,
                              void* d_out, int out_size, void* d_ws, size_t ws_size,
                              hipStream_t stream){
  const float* x    = (const float*)d_in[0];
  const int*   idx  = (const int*)d_in[1];
  const float* rule = (const float*)d_in[2];
  const float* W    = (const float*)d_in[3];
  const float* bias = (const float*)d_in[4];
  char* ws = (char*)d_ws;
  int* cnt  = (int*)(ws + CNT_OFF);
  int* rs   = (int*)(ws + RS_OFF);
  int* bs   = (int*)(ws + BS_OFF);
  int* rank = (int*)(ws + RANK_OFF);
  int* csr  = (int*)(ws + CSR_OFF);
  float* ldf = (float*)(ws + LDF_OFF);
  float* af  = (float*)(ws + AF_OFF);
  unsigned short* Bt   = (unsigned short*)(ws + BT_OFF);
  unsigned short* Abuf = (unsigned short*)(ws + A_OFF);
  float* out  = (float*)d_out;

  k_buildB_zero<<<dim3(768), 256, 0, stream>>>(rule, W, Bt, cnt,
      (int*)(Abuf + (size_t)NNODE * 512));
  k_hist<<<dim3((NEDGE / 4 + 255) / 256), 256, 0, stream>>>((const int4*)idx, cnt, (int4*)rank);
  k_scan1<<<dim3(25), 256, 0, stream>>>(cnt, rs, bs);
  k_scan3<<<dim3(196), 256, 0, stream>>>(rs, bs);
  k_scatter<<<dim3((NEDGE / 4 + 255) / 256), 256, 0, stream>>>(
      (const int4*)idx, (const int4*)rank, rs, csr);
  k_stats<<<dim3(12500), 256, 0, stream>>>(x, csr, rs, Abuf, ldf, af);
  k_gemm_fused<<<dim3(NBLK), 256, 0, stream>>>(Abuf, Bt, ldf, af, bias, out);
}

// Round 9
// 337.532 us; speedup vs baseline: 1.0260x; 1.0260x over previous
//
#include <hip/hip_runtime.h>
#include <hip/hip_bf16.h>
#include <cstdint>
#include <cstddef>

typedef __attribute__((ext_vector_type(4))) float f32x4;
typedef __attribute__((ext_vector_type(8))) short short8;
typedef __attribute__((ext_vector_type(4))) unsigned short u16x4;

static constexpr int NEDGE = 1600000;
static constexpr int NNODE = 50000;
static constexpr int MPAD  = 50048;   // 782*64
static constexpr float AVG_LOG_F = 3.4295121912749508f;

// ---- workspace layout (bytes) ----
static constexpr size_t CNT_OFF  = 0;          // 50000 i32
static constexpr size_t RS_OFF   = 200000;     // 50001 i32
static constexpr size_t BS_OFF   = 400064;     // 32 i32
static constexpr size_t RANK_OFF = 400192;     // 1600000 i32
static constexpr size_t CSR_OFF  = 6800192;    // 1600000 i32
static constexpr size_t LDF_OFF  = 13200192;   // 50000 f32
static constexpr size_t AF_OFF   = 13400192;   // 50000 f32
static constexpr size_t BT_OFF   = 13600192;   // 384*512 bf16
static constexpr size_t A_OFF    = 13993408;   // MPAD*512 bf16

__device__ __forceinline__ unsigned short f2bf(float f){
  union { __hip_bfloat16 h; unsigned short u; } cv;
  cv.h = __float2bfloat16(f);
  return cv.u;
}

// buildB + zero(cnt) + zero(A pad rows) in one launch (independent preludes).
// Bt[ncol][k]: ncol = s*128 + b*32 + l ; k = t*128 + p*32 + f
// Bt = sum_i rule[i,p,b] * W[i, s*128+t*32+f, l]
__global__ void k_buildB_zero(const float* __restrict__ rule, const float* __restrict__ W,
                              unsigned short* __restrict__ Bt,
                              int* __restrict__ cnt, int* __restrict__ apad){
  int id = blockIdx.x * 256 + threadIdx.x;
  if (id < NNODE) cnt[id] = 0;
  if (id < 48 * 256) apad[id] = 0;
  if (id >= 384 * 512) return;
  int k    = id & 511;
  int ncol = id >> 9;
  int t  = k >> 7;      int xf = k & 127;
  int p  = xf >> 5;     int f  = xf & 31;
  int s  = ncol >> 7;   int j  = ncol & 127;
  int bb = j >> 5;      int l  = j & 31;
  int kw = s * 128 + t * 32 + f;
  float acc = 0.f;
  #pragma unroll
  for (int i = 0; i < 4; ++i)
    acc += rule[i * 16 + p * 4 + bb] * W[(i * 384 + kw) * 32 + l];
  Bt[(size_t)ncol * 512 + k] = f2bf(acc);
}

// histogram + per-edge rank, 4 edges/thread
__global__ void k_hist(const int4* __restrict__ idx4, int* __restrict__ cnt,
                       int4* __restrict__ rank4){
  int e4 = blockIdx.x * 256 + threadIdx.x;
  if (e4 < NEDGE / 4){
    int4 n = idx4[e4];
    int4 r;
    r.x = atomicAdd(&cnt[n.x], 1);
    r.y = atomicAdd(&cnt[n.y], 1);
    r.z = atomicAdd(&cnt[n.z], 1);
    r.w = atomicAdd(&cnt[n.w], 1);
    rank4[e4] = r;
  }
}

__global__ void k_scan1(const int* __restrict__ cnt, int* __restrict__ rs, int* __restrict__ bs){
  __shared__ int lds[256];
  int t = threadIdx.x;
  int base = blockIdx.x * 2048 + t * 8;
  int v[8]; int s = 0;
  #pragma unroll
  for (int j = 0; j < 8; ++j){
    int i = base + j;
    int val = (i < NNODE) ? cnt[i] : 0;
    v[j] = val; s += val;
  }
  lds[t] = s;
  __syncthreads();
  for (int off = 1; off < 256; off <<= 1){
    int add = (t >= off) ? lds[t - off] : 0;
    __syncthreads();
    lds[t] += add;
    __syncthreads();
  }
  int run = lds[t] - s;   // exclusive prefix for this thread
  #pragma unroll
  for (int j = 0; j < 8; ++j){
    int i = base + j;
    if (i < NNODE) rs[i] = run;
    run += v[j];
  }
  if (t == 255) bs[blockIdx.x] = lds[255];
}

// adds block offsets; each block locally scans the 25 block-sums
__global__ void k_scan3(int* __restrict__ rs, const int* __restrict__ bs){
  __shared__ int pref[32];
  int t = threadIdx.x;
  if (t < 32){
    int v = (t < 25) ? bs[t] : 0;
    #pragma unroll
    for (int off = 1; off < 32; off <<= 1){
      int u = __shfl_up(v, off);
      if (t >= off) v += u;
    }
    pref[t] = v;  // inclusive scan
  }
  __syncthreads();
  int i = blockIdx.x * 256 + t;
  if (i < NNODE){
    int b = i >> 11;
    int add = (b == 0) ? 0 : pref[b - 1];
    rs[i] += add;
  }
  if (i == 0) rs[NNODE] = NEDGE;
}

// atomic-free scatter, 4 edges/thread
__global__ void k_scatter(const int4* __restrict__ idx4, const int4* __restrict__ rank4,
                          const int* __restrict__ rs, int* __restrict__ csr){
  int e4 = blockIdx.x * 256 + threadIdx.x;
  if (e4 < NEDGE / 4){
    int4 n = idx4[e4];
    int4 r = rank4[e4];
    int e = e4 * 4;
    csr[rs[n.x] + r.x] = e + 0;
    csr[rs[n.y] + r.y] = e + 1;
    csr[rs[n.z] + r.z] = e + 2;
    csr[rs[n.w] + r.w] = e + 3;
  }
}

// one wave per node: gather edges via CSR, compute mean/min/max/std per feature
__global__ __launch_bounds__(256) void k_stats(const float* __restrict__ x,
                const int* __restrict__ csr, const int* __restrict__ rs,
                unsigned short* __restrict__ A, float* __restrict__ ldf, float* __restrict__ af){
  int wid  = blockIdx.x * 4 + (threadIdx.x >> 6);
  int lane = threadIdx.x & 63;
  if (wid >= NNODE) return;
  int s0 = rs[wid], s1 = rs[wid + 1];
  int deg = s1 - s0;
  int sub = lane >> 5;          // which edge of the pair
  int fl  = (lane & 31) * 4;    // feature offset (4 floats)
  f32x4 sum = {0.f,0.f,0.f,0.f}, ssq = {0.f,0.f,0.f,0.f};
  float inf = __builtin_inff();
  f32x4 mn = {inf,inf,inf,inf}, mx = {-inf,-inf,-inf,-inf};
  for (int base = s0; base < s1; base += 64){
    int m = min(64, s1 - base);
    int myE = (lane < m) ? csr[base + lane] : 0;
    int pairs = (m + 1) >> 1;
    #pragma unroll 16
    for (int j = 0; j < pairs; ++j){
      int sl = j * 2 + sub;
      int ed = __shfl(myE, sl);
      // x rows are read exactly once -> keep them out of L2 (non-temporal)
      f32x4 v = __builtin_nontemporal_load((const f32x4*)(x + (size_t)ed * 128 + fl));
      if (sl < m){
        sum += v;
        ssq += v * v;
        #pragma unroll
        for (int c = 0; c < 4; ++c){ mn[c] = fminf(mn[c], v[c]); mx[c] = fmaxf(mx[c], v[c]); }
      }
    }
  }
  // merge the two half-wave partials (lane i <-> i^32 hold same features)
  #pragma unroll
  for (int c = 0; c < 4; ++c){
    sum[c] += __shfl_xor(sum[c], 32);
    ssq[c] += __shfl_xor(ssq[c], 32);
    mn[c]  = fminf(mn[c], __shfl_xor(mn[c], 32));
    mx[c]  = fmaxf(mx[c], __shfl_xor(mx[c], 32));
  }
  if (lane < 32){
    float invd = (deg > 0) ? (1.0f / (float)deg) : 1.0f;
    unsigned short* Arow = A + (size_t)wid * 512;
    u16x4 stv[4];
    #pragma unroll
    for (int c = 0; c < 4; ++c){
      float mean = sum[c] * invd;
      float var  = ssq[c] * invd - mean * mean;
      float sd   = sqrtf(fmaxf(var, 0.f) + 1e-5f);
      float lo   = (deg > 0) ? mn[c] : 0.f;
      float hi   = (deg > 0) ? mx[c] : 0.f;
      stv[0][c] = f2bf(mean);
      stv[1][c] = f2bf(lo);
      stv[2][c] = f2bf(hi);
      stv[3][c] = f2bf(sd);
    }
    #pragma unroll
    for (int t = 0; t < 4; ++t)
      *(u16x4*)(Arow + t * 128 + fl) = stv[t];
  }
  if (lane == 0){
    float ld = logf((float)deg + 1.0f);
    ldf[wid] = ld / AVG_LOG_F;
    af[wid]  = (deg == 0) ? 1.0f : (AVG_LOG_F / ld);
  }
}

// Fused GEMM + degree-scaler combine. 64-row tile, A staged once per block in
// LDS (stride 520 halves -> ds_read_b128 fragment reads 2 lanes/bank = free).
// B direct from L2/L3 (waves read disjoint cols).
__global__ __launch_bounds__(256) void k_gemm_fused(const unsigned short* __restrict__ A,
                                                    const unsigned short* __restrict__ Bt,
                                                    const float* __restrict__ ldf,
                                                    const float* __restrict__ af,
                                                    const float* __restrict__ bias,
                                                    float* __restrict__ out){
  __shared__ unsigned short Alds[64 * 520];   // 66560 B
  int w = threadIdx.x >> 6, lane = threadIdx.x & 63;
  int m0 = blockIdx.x * 64;
  int j0 = w * 32;
  int r16 = lane & 15, kq = lane >> 4;
  // stage A: 256 threads x 16B x 16 iters = 64 KB, coalesced
  {
    const unsigned short* src = A + (size_t)m0 * 512;
    int t = threadIdx.x;
    #pragma unroll
    for (int i = 0; i < 16; ++i){
      int off8 = (i * 256 + t) * 8;          // element offset, linear in source
      int r = off8 >> 9, c = off8 & 511;
      short8 v = *(const short8*)(src + off8);
      *(short8*)(&Alds[r * 520 + c]) = v;
    }
  }
  __syncthreads();
  f32x4 acc[4][2][3];   // [m-frag][col-frag][segment]
  #pragma unroll
  for (int m = 0; m < 4; ++m)
    #pragma unroll
    for (int nj = 0; nj < 2; ++nj)
      #pragma unroll
      for (int s = 0; s < 3; ++s) acc[m][nj][s] = (f32x4){0.f,0.f,0.f,0.f};
  const unsigned short* Bb = Bt + (size_t)(j0 + r16) * 512 + kq * 8;
  const unsigned short* Al = Alds + (size_t)r16 * 520 + kq * 8;
  for (int kk = 0; kk < 512; kk += 32){
    short8 a[4];
    #pragma unroll
    for (int m = 0; m < 4; ++m) a[m] = *(const short8*)(Al + m * 16 * 520 + kk);
    short8 b[3][2];
    #pragma unroll
    for (int s = 0; s < 3; ++s)
      #pragma unroll
      for (int nj = 0; nj < 2; ++nj)
        b[s][nj] = *(const short8*)(Bb + (size_t)(s * 128 + nj * 16) * 512 + kk);
    #pragma unroll
    for (int m = 0; m < 4; ++m)
      #pragma unroll
      for (int nj = 0; nj < 2; ++nj)
        #pragma unroll
        for (int s = 0; s < 3; ++s)
          acc[m][nj][s] = __builtin_amdgcn_mfma_f32_16x16x32_bf16(a[m], b[s][nj], acc[m][nj][s], 0, 0, 0);
  }
  int rq = kq;
  #pragma unroll
  for (int m = 0; m < 4; ++m){
    int row0 = m0 + m * 16 + rq * 4;
    float lv[4], av[4];
    #pragma unroll
    for (int r = 0; r < 4; ++r){
      int rr = min(row0 + r, NNODE - 1);
      lv[r] = ldf[rr];
      av[r] = af[rr];
    }
    #pragma unroll
    for (int nj = 0; nj < 2; ++nj){
      int col = j0 + nj * 16 + r16;
      float bb = bias[col];
      #pragma unroll
      for (int r = 0; r < 4; ++r){
        int row = row0 + r;
        if (row < NNODE)
          out[(size_t)row * 128 + col] =
            acc[m][nj][0][r] + lv[r] * acc[m][nj][1][r] + av[r] * acc[m][nj][2][r] + bb;
      }
    }
  }
}

extern "C" void kernel_launch(void* const* d_in, const int* in_sizes, int n_in,
                              void* d_out, int out_size, void* d_ws, size_t ws_size,
                              hipStream_t stream){
  const float* x    = (const float*)d_in[0];
  const int*   idx  = (const int*)d_in[1];
  const float* rule = (const float*)d_in[2];
  const float* W    = (const float*)d_in[3];
  const float* bias = (const float*)d_in[4];
  char* ws = (char*)d_ws;
  int* cnt  = (int*)(ws + CNT_OFF);
  int* rs   = (int*)(ws + RS_OFF);
  int* bs   = (int*)(ws + BS_OFF);
  int* rank = (int*)(ws + RANK_OFF);
  int* csr  = (int*)(ws + CSR_OFF);
  float* ldf = (float*)(ws + LDF_OFF);
  float* af  = (float*)(ws + AF_OFF);
  unsigned short* Bt   = (unsigned short*)(ws + BT_OFF);
  unsigned short* Abuf = (unsigned short*)(ws + A_OFF);
  float* out  = (float*)d_out;

  k_buildB_zero<<<dim3(768), 256, 0, stream>>>(rule, W, Bt, cnt,
      (int*)(Abuf + (size_t)NNODE * 512));
  k_hist<<<dim3((NEDGE / 4 + 255) / 256), 256, 0, stream>>>((const int4*)idx, cnt, (int4*)rank);
  k_scan1<<<dim3(25), 256, 0, stream>>>(cnt, rs, bs);
  k_scan3<<<dim3(196), 256, 0, stream>>>(rs, bs);
  k_scatter<<<dim3((NEDGE / 4 + 255) / 256), 256, 0, stream>>>(
      (const int4*)idx, (const int4*)rank, rs, csr);
  k_stats<<<dim3(12500), 256, 0, stream>>>(x, csr, rs, Abuf, ldf, af);
  k_gemm_fused<<<dim3(MPAD / 64), 256, 0, stream>>>(Abuf, Bt, ldf, af, bias, out);
}